// Round 5
// baseline (3882.708 us; speedup 1.0000x reference)
//
#include <hip/hip_runtime.h>
#include <math.h>

// RNN scan: h_t = tanh(h_{t-1} @ Whh + b_hh + x_t * Wxh + b_xh), out = h_T @ Wout + b_out
// B=16384 rows, T=1024 steps, H=32 hidden.
//
// Design (round 5): R4's DPP-systolic fp32, with the register allocator UNCAPPED.
//  - R3/R4 post-mortem: __launch_bounds__(256,4) -> amdgpu-waves-per-eu=[4,8];
//    the scheduler targets the MAX of the range (8 waves/EU -> 64-VGPR cap) and
//    scratch-spills the 64-entry weight table instead of relaxing to 4 waves.
//    Evidence: VGPR=64, WRITE_SIZE 137 MB (= one-time scratch write of
//    262144 thr x 256 B), FETCH 12.6 GB (= per-step scratch re-read, 81% L2 hit),
//    VALUBusy 15%. Fix: pin the range with amdgpu_waves_per_eu(4,4) -> budget
//    exactly 128 VGPRs; est. peak pressure ~105.
//  - each 16-lane DPP row owns one batch row; lane p holds h_p and h_{p+16}.
//  - dot product via row_ror:k DPP (k=0..15): dst lane i gets src lane (i-k)&15
//    (verified by R3/R4 correctness).
//  - x read from global, 4-step float4 register prefetch.
//  - 1024 blocks x 256 thr = 4096 waves; 128-VGPR cap keeps 4 blocks/CU.

constexpr int Tlen = 1024;
constexpr int Hdim = 32;
constexpr int NBLOCKS = 1024;

__device__ __forceinline__ float fast_tanh(float x) {
    // tanh(x) = sign(x) * (1 - e) / (1 + e),  e = exp(-2|x|); e underflows to 0
    // for large |x| -> result +/-1 exactly. approx err ~1e-6.
    float ax = __builtin_fabsf(x);
    float e  = __builtin_amdgcn_exp2f(ax * -2.8853900817779268f); // exp(-2ax)
    float num = 1.0f - e;
    float den = 1.0f + e;
    float r = num * __builtin_amdgcn_rcpf(den);
    return __builtin_copysignf(r, x);
}

// row_ror:K within 16-lane DPP row: dst lane i gets src lane (i-K)&15.
template <int CTRL>
__device__ __forceinline__ float ror16(float v) {
    int iv = __builtin_bit_cast(int, v);
    int r = __builtin_amdgcn_update_dpp(iv, iv, CTRL, 0xF, 0xF, true);
    return __builtin_bit_cast(float, r);
}

__global__ __launch_bounds__(256) __attribute__((amdgpu_waves_per_eu(4, 4)))
void rnn_dpp_kernel(const float* __restrict__ x,    // [B,T]
                    const float* __restrict__ Wxh,  // [1,H]
                    const float* __restrict__ b_xh, // [H]
                    const float* __restrict__ Whh,  // [H,H] row-major (i,j)
                    const float* __restrict__ b_hh, // [H]
                    const float* __restrict__ Wout, // [H,1]
                    const float* __restrict__ b_out,// [1]
                    float* __restrict__ out)        // [B,1]
{
    const int tid = threadIdx.x;
    const int p   = tid & 15;                 // lane within DPP row
    const int grp = tid >> 4;                 // 16 batch rows per block
    const int row = blockIdx.x * 16 + grp;
    const float* xr = x + (size_t)row * Tlen;

    // Weight preload, rotation order: at slot K, row_ror:K delivers h_m with
    // m=(p-K)&15 (and h_{m+16}). Lane p accumulates outputs p and p+16.
    // 64 named scalars; with the 128-VGPR budget these stay in registers.
#define DECLW(K)                                                          \
    const float wa1_##K = Whh[(((p - K) & 15)     ) * Hdim + p     ];     \
    const float wa2_##K = Whh[(((p - K) & 15) + 16) * Hdim + p     ];     \
    const float wb1_##K = Whh[(((p - K) & 15)     ) * Hdim + p + 16];     \
    const float wb2_##K = Whh[(((p - K) & 15) + 16) * Hdim + p + 16];
    DECLW(0)  DECLW(1)  DECLW(2)  DECLW(3)
    DECLW(4)  DECLW(5)  DECLW(6)  DECLW(7)
    DECLW(8)  DECLW(9)  DECLW(10) DECLW(11)
    DECLW(12) DECLW(13) DECLW(14) DECLW(15)
#undef DECLW

    const float ba  = b_hh[p]      + b_xh[p];
    const float bb  = b_hh[p + 16] + b_xh[p + 16];
    const float wxa = Wxh[p];
    const float wxb = Wxh[p + 16];

    float h1 = 0.0f, h2 = 0.0f;               // h_p, h_{p+16} of this batch row
    float4 xq = *(const float4*)xr;           // current 4-step x chunk

#define RNN_K(K)                                                          \
    {                                                                     \
        float r1 = ror16<0x120 + K>(h1);                                  \
        float r2 = ror16<0x120 + K>(h2);                                  \
        a1 = fmaf(r1, wa1_##K, a1);  a2 = fmaf(r2, wa2_##K, a2);          \
        b1 = fmaf(r1, wb1_##K, b1);  b2 = fmaf(r2, wb2_##K, b2);          \
    }
#define DO_STEP(XV)                                                       \
    {                                                                     \
        float a1 = fmaf((XV), wxa, ba);                                   \
        float b1 = fmaf((XV), wxb, bb);                                   \
        float a2 = 0.0f, b2 = 0.0f;                                       \
        a1 = fmaf(h1, wa1_0, a1);  a2 = fmaf(h2, wa2_0, a2);              \
        b1 = fmaf(h1, wb1_0, b1);  b2 = fmaf(h2, wb2_0, b2);              \
        RNN_K(1)  RNN_K(2)  RNN_K(3)  RNN_K(4)                            \
        RNN_K(5)  RNN_K(6)  RNN_K(7)  RNN_K(8)                            \
        RNN_K(9)  RNN_K(10) RNN_K(11) RNN_K(12)                           \
        RNN_K(13) RNN_K(14) RNN_K(15)                                     \
        h1 = fast_tanh(a1 + a2);                                          \
        h2 = fast_tanh(b1 + b2);                                          \
    }

    #pragma unroll 1
    for (int tc = 0; tc < Tlen; tc += 4) {
        // prefetch next chunk (clamped on last iter; value unused then)
        const int tn = (tc + 4 < Tlen) ? (tc + 4) : tc;
        float4 xn = *(const float4*)(xr + tn);
        DO_STEP(xq.x)
        DO_STEP(xq.y)
        DO_STEP(xq.z)
        DO_STEP(xq.w)
        xq = xn;
    }
#undef DO_STEP
#undef RNN_K

    // out[row] = sum_p (h1*Wout[p] + h2*Wout[p+16]) + b_out, reduced over the
    // 16-lane group (xor offsets 1,2,4,8 stay inside the group).
    float v = fmaf(h1, Wout[p], h2 * Wout[p + 16]);
    v += __shfl_xor(v, 1, 64);
    v += __shfl_xor(v, 2, 64);
    v += __shfl_xor(v, 4, 64);
    v += __shfl_xor(v, 8, 64);
    if (p == 0) out[row] = v + b_out[0];
}

extern "C" void kernel_launch(void* const* d_in, const int* in_sizes, int n_in,
                              void* d_out, int out_size, void* d_ws, size_t ws_size,
                              hipStream_t stream) {
    const float* x     = (const float*)d_in[0];
    const float* Wxh   = (const float*)d_in[1];
    const float* b_xh  = (const float*)d_in[2];
    const float* Whh   = (const float*)d_in[3];
    const float* b_hh  = (const float*)d_in[4];
    const float* Wout  = (const float*)d_in[5];
    const float* b_out = (const float*)d_in[6];
    float* out = (float*)d_out;

    rnn_dpp_kernel<<<NBLOCKS, 256, 0, stream>>>(x, Wxh, b_xh, Whh, b_hh, Wout,
                                                b_out, out);
}

// Round 6
// 944.910 us; speedup vs baseline: 4.1091x; 4.1091x over previous
//
#include <hip/hip_runtime.h>
#include <math.h>

// RNN scan: h_t = tanh(h_{t-1} @ Whh + b_hh + x_t * Wxh + b_xh), out = h_T @ Wout + b_out
// B=16384 rows, T=1024 steps, H=32 hidden.
//
// Design (round 6): 32-lane-per-row DPP-systolic fp32, sized UNDER the 64-VGPR cap.
//  - R3-R5 lesson: this toolchain pins 256-thread kernels at a 64-VGPR budget;
//    neither __launch_bounds__(256,4) nor amdgpu_waves_per_eu(4,4) lifts it —
//    the 64-weight/lane layout spills to scratch (12.6 GB HBM fetch, VALU 15%).
//    Fix: halve per-lane weight state to 32 regs -> total pressure ~55 < 64.
//    Bonus: VGPR<=64 allows 8 waves/EU (was 4) -> better latency hiding.
//  - mapping: 32-lane group owns one batch row; lane c (tid&31) owns h_c.
//    Own-half sum: 16 rotated fmacs via row_ror:K DPP (dst lane i <- (i-K)&15,
//    verified R3/R4). Cross-half: one __shfl_xor(h,16) per step grabs the
//    partner component, then 16 more rotated fmacs.
//    Each rotation feeds EXACTLY ONE fma (dest==addend) -> v_fmac_f32_dpp fold.
//  - x: float2 register prefetch per 2 steps (32 lanes share one address).
//  - 2048 blocks x 256 thr = 8192 waves = 8/SIMD, fully resident.

constexpr int Tlen = 1024;
constexpr int Hdim = 32;
constexpr int NBLOCKS = 2048;

__device__ __forceinline__ float fast_tanh(float x) {
    // tanh(x) = sign(x) * (1 - e) / (1 + e),  e = exp(-2|x|); e underflows to 0
    // for large |x| -> result +/-1 exactly. approx err ~1e-6.
    float ax = __builtin_fabsf(x);
    float e  = __builtin_amdgcn_exp2f(ax * -2.8853900817779268f); // exp(-2ax)
    float num = 1.0f - e;
    float den = 1.0f + e;
    float r = num * __builtin_amdgcn_rcpf(den);
    return __builtin_copysignf(r, x);
}

// row_ror:K within 16-lane DPP row: dst lane i gets src lane (i-K)&15.
template <int CTRL>
__device__ __forceinline__ float ror16(float v) {
    int iv = __builtin_bit_cast(int, v);
    int r = __builtin_amdgcn_update_dpp(iv, iv, CTRL, 0xF, 0xF, true);
    return __builtin_bit_cast(float, r);
}

__global__ __launch_bounds__(256)
void rnn_dpp_kernel(const float* __restrict__ x,    // [B,T]
                    const float* __restrict__ Wxh,  // [1,H]
                    const float* __restrict__ b_xh, // [H]
                    const float* __restrict__ Whh,  // [H,H] row-major (i,j)
                    const float* __restrict__ b_hh, // [H]
                    const float* __restrict__ Wout, // [H,1]
                    const float* __restrict__ b_out,// [1]
                    float* __restrict__ out)        // [B,1]
{
    const int tid = threadIdx.x;
    const int c   = tid & 31;                 // output column owned by this lane
    const int p   = c & 15;                   // position within 16-lane DPP row
    const int q   = (c >> 4) & 1;             // which 16-half this lane sits in
    const int g   = tid >> 5;                 // 8 batch rows per block
    const int row = blockIdx.x * 8 + g;
    const float* xr = x + (size_t)row * Tlen;

    // 32 named weight scalars (VGPR-resident under the 64 cap):
    //  own-half slot K multiplies h_{((p-K)&15) + 16q};
    //  cross-half slot K multiplies h_{((p-K)&15) + 16(1-q)} (value arrives via
    //  shfl_xor(16) then row_ror:K).
#define DECLW(K)                                                            \
    const float wo_##K = Whh[(((p - K) & 15) + 16 * q)       * Hdim + c];   \
    const float wc_##K = Whh[(((p - K) & 15) + 16 * (1 - q)) * Hdim + c];
    DECLW(0)  DECLW(1)  DECLW(2)  DECLW(3)
    DECLW(4)  DECLW(5)  DECLW(6)  DECLW(7)
    DECLW(8)  DECLW(9)  DECLW(10) DECLW(11)
    DECLW(12) DECLW(13) DECLW(14) DECLW(15)
#undef DECLW

    const float bc = b_hh[c] + b_xh[c];
    const float wx = Wxh[c];

    float h  = 0.0f;                          // h_c of this batch row
    float hx = 0.0f;                          // partner h_{p+16(1-q)} (h0=0)

    float2 xq = *(const float2*)xr;           // current 2-step x chunk

#define RNN_K(K)                                                            \
    ao = fmaf(ror16<0x120 + K>(h),  wo_##K, ao);                            \
    ac = fmaf(ror16<0x120 + K>(hx), wc_##K, ac);

#define DO_STEP(XV)                                                         \
    {                                                                       \
        float ao = fmaf((XV), wx, bc);                                      \
        ao = fmaf(h, wo_0, ao);                                             \
        float ac = hx * wc_0;                                               \
        RNN_K(1)  RNN_K(2)  RNN_K(3)  RNN_K(4)                              \
        RNN_K(5)  RNN_K(6)  RNN_K(7)  RNN_K(8)                              \
        RNN_K(9)  RNN_K(10) RNN_K(11) RNN_K(12)                             \
        RNN_K(13) RNN_K(14) RNN_K(15)                                       \
        h  = fast_tanh(ao + ac);                                            \
        hx = __shfl_xor(h, 16, 64);                                         \
    }

    #pragma unroll 1
    for (int tc = 0; tc < Tlen; tc += 2) {
        // prefetch next chunk (clamped on last iter; value unused then)
        const int tn = (tc + 2 < Tlen) ? (tc + 2) : tc;
        float2 xn = *(const float2*)(xr + tn);
        DO_STEP(xq.x)
        DO_STEP(xq.y)
        xq = xn;
    }
#undef DO_STEP
#undef RNN_K

    // out[row] = sum_c h_c * Wout[c] + b_out, reduced over the 32-lane group
    // (xor offsets 1..16 stay inside the group).
    float v = h * Wout[c];
    v += __shfl_xor(v, 1, 64);
    v += __shfl_xor(v, 2, 64);
    v += __shfl_xor(v, 4, 64);
    v += __shfl_xor(v, 8, 64);
    v += __shfl_xor(v, 16, 64);
    if (c == 0) out[row] = v + b_out[0];
}

extern "C" void kernel_launch(void* const* d_in, const int* in_sizes, int n_in,
                              void* d_out, int out_size, void* d_ws, size_t ws_size,
                              hipStream_t stream) {
    const float* x     = (const float*)d_in[0];
    const float* Wxh   = (const float*)d_in[1];
    const float* b_xh  = (const float*)d_in[2];
    const float* Whh   = (const float*)d_in[3];
    const float* b_hh  = (const float*)d_in[4];
    const float* Wout  = (const float*)d_in[5];
    const float* b_out = (const float*)d_in[6];
    float* out = (float*)d_out;

    rnn_dpp_kernel<<<NBLOCKS, 256, 0, stream>>>(x, Wxh, b_xh, Whh, b_hh, Wout,
                                                b_out, out);
}